// Round 11
// baseline (480.591 us; speedup 1.0000x reference)
//
#include <hip/hip_runtime.h>
#include <hip/hip_bf16.h>
#include <stdint.h>

// Problem constants (B=4, S=2048, H=1024, E=8, K=2)
#define E_    8
#define H_    1024
#define NTOK  8192           // B*S
#define KSEL  2
#define NSLOT (NTOK * KSEL)  // 16384

typedef __attribute__((ext_vector_type(8))) short   short8_t;  // 8 bf16 in 4 VGPRs
typedef __attribute__((ext_vector_type(4))) float   f32x4;

// GEMM tiling: 256x256 tile, BK=64, 8 waves (2Mx4N), dbuf LDS = 128KB, 8-phase/2-tile.
// m198 configuration: LINEAR LDS (no swizzle anywhere) — gload_lds source is
// monotone per lane (stream-to-LDS path intact); 16-way ds_read conflicts
// accepted (m198: 1167 TF with exactly this tradeoff).
#define BM 256
#define BN 256
#define BK 64
#define MAXMT 72             // ceil-sum of per-expert M-tiles <= 64+7=71
#define NT    (H_ / BN)      // 4 N-tiles
#define NWG   (MAXMT * NT)   // 288, divisible by 8 (bijective XCD swizzle)

// ---- workspace layout (bytes) ----
#define CNT_OFF   0
#define CUR_OFF   64
#define OFFS_OFF  128
#define TOFF_OFF  256
#define TOK_OFF   1024                     // NSLOT ints
#define WSL_OFF   (TOK_OFF + NSLOT * 4)    // NSLOT floats
#define AG_ROWS   (NSLOT + 256)
#define AG_OFF    (1 << 18)
#define H1_OFF    (AG_OFF + AG_ROWS * H_ * 2)
#define W1T_OFF   (H1_OFF + AG_ROWS * H_ * 2)
#define W2T_OFF   (W1T_OFF + E_ * H_ * H_ * 2)

// ---------------------------------------------------------------------------
__device__ __forceinline__ void async_copy16(const void* g, void* l) {
  __builtin_amdgcn_global_load_lds(
      (const __attribute__((address_space(1))) unsigned int*)g,
      (__attribute__((address_space(3))) unsigned int*)l,
      16, 0, 0);
}

// ---------------------------------------------------------------------------
__global__ void route_count(const int* __restrict__ idx, int* __restrict__ cnt) {
  int p = blockIdx.x * 256 + threadIdx.x;
  if (p < NSLOT) atomicAdd(&cnt[idx[p]], 1);
}

__global__ void route_scan(const int* __restrict__ cnt, int* __restrict__ offs,
                           int* __restrict__ cur, int* __restrict__ toff) {
  if (threadIdx.x == 0) {
    int s = 0, t = 0;
    for (int e = 0; e < E_; ++e) {
      offs[e] = s; cur[e] = s; toff[e] = t;
      s += cnt[e];
      t += (cnt[e] + BM - 1) / BM;
    }
    offs[E_] = s; toff[E_] = t;
  }
}

__global__ void route_scatter(const int* __restrict__ idx, const float* __restrict__ tkw,
                              int* __restrict__ cur, int* __restrict__ tok,
                              float* __restrict__ wsl) {
  int p = blockIdx.x * 256 + threadIdx.x;
  if (p < NSLOT) {
    int e = idx[p];
    int pos = atomicAdd(&cur[e], 1);
    tok[pos] = p >> 1;
    wsl[pos] = tkw[p];
  }
}

// ---------------------------------------------------------------------------
// wt[e][f][h] = (bf16) w[e][h][f]
__global__ void transpose_cast(const float* __restrict__ w1, const float* __restrict__ w2,
                               __hip_bfloat16* __restrict__ wt1, __hip_bfloat16* __restrict__ wt2) {
  __shared__ float t[32][33];
  const int z = blockIdx.z;
  const float* W = (z < E_ ? w1 : w2) + ((size_t)(z & 7) << 20);
  __hip_bfloat16* WT = (z < E_ ? wt1 : wt2) + ((size_t)(z & 7) << 20);
  const int h0 = blockIdx.y * 32, f0 = blockIdx.x * 32;
  const int tx = threadIdx.x, ty = threadIdx.y;  // 32 x 8
#pragma unroll
  for (int i = 0; i < 32; i += 8)
    t[ty + i][tx] = W[(size_t)(h0 + ty + i) * H_ + f0 + tx];
  __syncthreads();
#pragma unroll
  for (int i = 0; i < 32; i += 8)
    WT[(size_t)(f0 + ty + i) * H_ + h0 + tx] = __float2bfloat16(t[tx][ty + i]);
}

// ---------------------------------------------------------------------------
__global__ void gather_cast(const float* __restrict__ x, const int* __restrict__ tok,
                            __hip_bfloat16* __restrict__ Ag) {
  const int c = threadIdx.x;
  for (int p = blockIdx.x; p < NSLOT; p += gridDim.x) {
    const int t = tok[p];
    float4 v = ((const float4*)(x + (size_t)t * H_))[c];
    union { __hip_bfloat16 h[4]; uint2 u; } cv;
    cv.h[0] = __float2bfloat16(v.x);
    cv.h[1] = __float2bfloat16(v.y);
    cv.h[2] = __float2bfloat16(v.z);
    cv.h[3] = __float2bfloat16(v.w);
    *reinterpret_cast<uint2*>(Ag + (size_t)p * H_ + (size_t)c * 4) = cv.u;
  }
}

// ---------------------------------------------------------------------------
// Grouped GEMM, 256x256, 8 waves (2Mx4N), 8-phase (4 phases/K-tile) schedule.
// Counted vmcnt at q3 only (round-7 ledger, verified correct). LINEAR LDS.
template <int EPI>
__launch_bounds__(512, 1)
__global__ void moe_gemm(const __hip_bfloat16* __restrict__ Abase,
                         const __hip_bfloat16* __restrict__ Wt,   // [E][H][H] (f-major)
                         const float* __restrict__ bias,          // [E][H]
                         __hip_bfloat16* __restrict__ h1out,
                         float* __restrict__ out,
                         const int* __restrict__ cnt, const int* __restrict__ offs,
                         const int* __restrict__ toff,
                         const int* __restrict__ tok, const float* __restrict__ wsl) {
  // T1: bijective XCD swizzle (NWG % 8 == 0)
  const int wgid = (blockIdx.x & 7) * (NWG / 8) + (blockIdx.x >> 3);
  const int bt = wgid >> 2;            // flat M-tile id across experts
  const int nt = wgid & 3;             // N-tile
  if (bt >= toff[E_]) return;
  int e = 0;
  while (bt >= toff[e + 1]) ++e;
  const int mt = bt - toff[e];
  const int count = cnt[e];

  const int tid = threadIdx.x;
  const int wid = tid >> 6, lane = tid & 63;
  const int wm = wid >> 2, wn = wid & 3;  // 2x4 waves -> per-wave 128x64 output
  const int l15 = lane & 15, hi = lane >> 4;

  const size_t Arow0 = (size_t)(offs[e] + mt * BM);
  const __hip_bfloat16* Aexp = Abase + Arow0 * H_;
  const __hip_bfloat16* Bexp = Wt + ((size_t)e << 20) + (size_t)(nt * BN) * H_;

  __shared__ __hip_bfloat16 smA[2][BM * BK];  // 32 KB each
  __shared__ __hip_bfloat16 smB[2][BN * BK];  // total 128 KB

  // ---- staging: LINEAR both sides. Per wave: 8 rows x 128B contiguous,
  //      monotone lane->address (m97-proven stream-to-LDS pattern).
  const int rl  = tid >> 3;           // 0..63
  const int sun = (tid & 7) * 8;      // element offset within BK row

  // A item j: rows {32j..32j+31} and {128+32j..+31}  (read at phase j)
  auto stageA = [&](int slot, int kt, int j) {
    const int row = (rl < 32) ? (j * 32 + rl) : (128 + j * 32 + (rl - 32));
    async_copy16(Aexp + (size_t)row * H_ + kt * BK + sun,
                 &smA[slot][row * BK + (tid & 7) * 8]);
  };
  // B item j: rows {64j..64j+63}  (all B read at phase 0)
  auto stageB = [&](int slot, int kt, int j) {
    const int row = j * 64 + rl;
    async_copy16(Bexp + (size_t)row * H_ + kt * BK + sun,
                 &smB[slot][row * BK + (tid & 7) * 8]);
  };

  f32x4 acc[8][4];
#pragma unroll
  for (int mi = 0; mi < 8; ++mi)
#pragma unroll
    for (int ni = 0; ni < 4; ++ni) acc[mi][ni] = f32x4{0.f, 0.f, 0.f, 0.f};

  const int KT = H_ / BK;  // 16

  // ---- prologue: tile0 full (8 items), tile1 B0-3 + A0,A1 (6 items) ----
#pragma unroll
  for (int j = 0; j < 4; ++j) stageB(0, 0, j);
#pragma unroll
  for (int j = 0; j < 4; ++j) stageA(0, 0, j);
#pragma unroll
  for (int j = 0; j < 4; ++j) stageB(1, 1, j);
  stageA(1, 1, 0);
  stageA(1, 1, 1);
  asm volatile("s_waitcnt vmcnt(6)" ::: "memory");  // tile0's 8 items landed
  __builtin_amdgcn_s_barrier();
  __builtin_amdgcn_sched_barrier(0);

  for (int T = 0; T < KT; ++T) {
    const int cs = T & 1;
    short8_t bfr[4][2];
#pragma unroll
    for (int q = 0; q < 4; ++q) {
      // --- ds_read this phase's register subtile (slot cs resident) ---
      short8_t afr[2][2];
#pragma unroll
      for (int m2 = 0; m2 < 2; ++m2)
#pragma unroll
        for (int ks = 0; ks < 2; ++ks)
          afr[m2][ks] = *(const short8_t*)&smA[cs][(wm * 128 + (2 * q + m2) * 16 + l15) * BK + (ks * 4 + hi) * 8];
      if (q == 0) {
#pragma unroll
        for (int ni = 0; ni < 4; ++ni)
#pragma unroll
          for (int ks = 0; ks < 2; ++ks)
            bfr[ni][ks] = *(const short8_t*)&smB[cs][(wn * 64 + ni * 16 + l15) * BK + (ks * 4 + hi) * 8];
      }
      // --- stage 2 items into the region read in an earlier phase ---
      if (q == 0)      { if (T + 1 < KT) { stageA(cs ^ 1, T + 1, 2); stageA(cs ^ 1, T + 1, 3); } }
      else if (q == 1) { if (T + 2 < KT) { stageB(cs,     T + 2, 0); stageB(cs,     T + 2, 1); } }
      else if (q == 2) { if (T + 2 < KT) { stageB(cs,     T + 2, 2); stageB(cs,     T + 2, 3); } }
      else {
        if (T + 2 < KT) { stageA(cs, T + 2, 0); stageA(cs, T + 2, 1); }
        // T4: K-tile boundary wait, ONCE per tile, counted (never 0 until taper).
        if (T >= KT - 2) asm volatile("s_waitcnt vmcnt(0)" ::: "memory");
        else             asm volatile("s_waitcnt vmcnt(6)" ::: "memory");
      }
      __builtin_amdgcn_s_barrier();
      asm volatile("s_waitcnt lgkmcnt(0)" ::: "memory");
      __builtin_amdgcn_sched_barrier(0);   // rule 18: MFMA/reads must not cross the wait
      __builtin_amdgcn_s_setprio(1);       // T5
#pragma unroll
      for (int m2 = 0; m2 < 2; ++m2)
#pragma unroll
        for (int ni = 0; ni < 4; ++ni)
#pragma unroll
          for (int ks = 0; ks < 2; ++ks)
            acc[2 * q + m2][ni] = __builtin_amdgcn_mfma_f32_16x16x32_bf16(
                afr[m2][ks], bfr[ni][ks], acc[2 * q + m2][ni], 0, 0, 0);
      __builtin_amdgcn_s_setprio(0);
      __builtin_amdgcn_sched_barrier(0);
      __builtin_amdgcn_s_barrier();        // frees this phase's read-region
      __builtin_amdgcn_sched_barrier(0);   // next phase's ds_reads must not hoist above
    }
  }

  const int colb = nt * BN + wn * 64;
  if constexpr (EPI == 0) {
#pragma unroll
    for (int ni = 0; ni < 4; ++ni) {
      const int col = colb + ni * 16 + l15;
      const float bv = bias[e * H_ + col];
#pragma unroll
      for (int mi = 0; mi < 8; ++mi)
#pragma unroll
        for (int r = 0; r < 4; ++r) {
          const int lr = wm * 128 + mi * 16 + hi * 4 + r;
          if (mt * BM + lr < count) {
            float v = acc[mi][ni][r] + bv;
            h1out[(Arow0 + lr) * H_ + col] = __float2bfloat16(fmaxf(v, 0.f));
          }
        }
    }
  } else {
#pragma unroll
    for (int mi = 0; mi < 8; ++mi)
#pragma unroll
      for (int r = 0; r < 4; ++r) {
        const int lr = wm * 128 + mi * 16 + hi * 4 + r;
        if (mt * BM + lr < count) {
          const int p = (int)Arow0 + lr;
          const int t = tok[p];
          const float w = wsl[p];
#pragma unroll
          for (int ni = 0; ni < 4; ++ni) {
            const int col = colb + ni * 16 + l15;
            float v = (acc[mi][ni][r] + bias[e * H_ + col]) * w;
            atomicAdd(out + (size_t)t * H_ + col, v);
          }
        }
      }
  }
}

// ---------------------------------------------------------------------------
extern "C" void kernel_launch(void* const* d_in, const int* in_sizes, int n_in,
                              void* d_out, int out_size, void* d_ws, size_t ws_size,
                              hipStream_t stream) {
  const float* x   = (const float*)d_in[0];
  const int*   idx = (const int*)d_in[1];
  const float* tkw = (const float*)d_in[2];
  const float* w1  = (const float*)d_in[3];
  const float* b1  = (const float*)d_in[4];
  const float* w2  = (const float*)d_in[5];
  const float* b2  = (const float*)d_in[6];
  float* out = (float*)d_out;

  uint8_t* ws = (uint8_t*)d_ws;
  int*   cnt  = (int*)(ws + CNT_OFF);
  int*   cur  = (int*)(ws + CUR_OFF);
  int*   offs = (int*)(ws + OFFS_OFF);
  int*   toff = (int*)(ws + TOFF_OFF);
  int*   tok  = (int*)(ws + TOK_OFF);
  float* wsl  = (float*)(ws + WSL_OFF);
  __hip_bfloat16* Ag  = (__hip_bfloat16*)(ws + AG_OFF);
  __hip_bfloat16* h1  = (__hip_bfloat16*)(ws + H1_OFF);
  __hip_bfloat16* w1t = (__hip_bfloat16*)(ws + W1T_OFF);
  __hip_bfloat16* w2t = (__hip_bfloat16*)(ws + W2T_OFF);

  hipMemsetAsync(ws, 0, 1024, stream);
  hipMemsetAsync(d_out, 0, (size_t)out_size * sizeof(float), stream);

  transpose_cast<<<dim3(H_ / 32, H_ / 32, 2 * E_), dim3(32, 8), 0, stream>>>(w1, w2, w1t, w2t);

  route_count<<<NSLOT / 256, 256, 0, stream>>>(idx, cnt);
  route_scan<<<1, 64, 0, stream>>>(cnt, offs, cur, toff);
  route_scatter<<<NSLOT / 256, 256, 0, stream>>>(idx, tkw, cur, tok, wsl);
  gather_cast<<<2048, 256, 0, stream>>>(x, tok, Ag);

  moe_gemm<0><<<NWG, 512, 0, stream>>>(Ag, w1t, b1, h1, nullptr, cnt, offs, toff, tok, wsl);
  moe_gemm<1><<<NWG, 512, 0, stream>>>(h1, w2t, b2, nullptr, out, cnt, offs, toff, tok, wsl);
}

// Round 12
// 331.736 us; speedup vs baseline: 1.4487x; 1.4487x over previous
//
#include <hip/hip_runtime.h>
#include <hip/hip_bf16.h>
#include <stdint.h>

// Problem constants (B=4, S=2048, H=1024, E=8, K=2)
#define E_    8
#define H_    1024
#define NTOK  8192           // B*S
#define KSEL  2
#define NSLOT (NTOK * KSEL)  // 16384

typedef __attribute__((ext_vector_type(8))) short   short8_t;  // 8 bf16 in 4 VGPRs
typedef __attribute__((ext_vector_type(4))) float   f32x4;

// GEMM tiling: 128x128, BK=64, 4 waves. Reg-staged (global->VGPR->ds_write),
// PADDED LDS (stride 72 elems -> conflict-free b128 r/w), SINGLE buffer with
// RAW barriers (lgkmcnt-only fences): global loads for kt+1 issued inside
// compute(kt) stay in flight ACROSS the barrier (ds_write's per-register
// counted vmcnt wait = T4's mechanism). 36.9KB LDS + lb(256,3) -> 3-4 blocks/CU.
#define BM 128
#define BN 128
#define BK 64
#define LDP 72               // padded row stride (elems)
#define MAXMT 136            // ceil-sum of per-expert M-tiles <= 128+7=135
#define NT    (H_ / BN)      // 8 N-tiles
#define NWG   (MAXMT * NT)   // 1088, divisible by 8 (bijective XCD swizzle)

// ---- workspace layout (bytes) ----
#define CNT_OFF   0
#define CUR_OFF   64
#define OFFS_OFF  128
#define TOFF_OFF  256
#define TOK_OFF   1024                     // NSLOT ints
#define WSL_OFF   (TOK_OFF + NSLOT * 4)    // NSLOT floats
#define AG_ROWS   (NSLOT + 256)
#define AG_OFF    (1 << 18)
#define H1_OFF    (AG_OFF + AG_ROWS * H_ * 2)
#define W1T_OFF   (H1_OFF + AG_ROWS * H_ * 2)
#define W2T_OFF   (W1T_OFF + E_ * H_ * H_ * 2)

// ---------------------------------------------------------------------------
__global__ void route_count(const int* __restrict__ idx, int* __restrict__ cnt) {
  int p = blockIdx.x * 256 + threadIdx.x;
  if (p < NSLOT) atomicAdd(&cnt[idx[p]], 1);
}

__global__ void route_scan(const int* __restrict__ cnt, int* __restrict__ offs,
                           int* __restrict__ cur, int* __restrict__ toff) {
  if (threadIdx.x == 0) {
    int s = 0, t = 0;
    for (int e = 0; e < E_; ++e) {
      offs[e] = s; cur[e] = s; toff[e] = t;
      s += cnt[e];
      t += (cnt[e] + BM - 1) / BM;
    }
    offs[E_] = s; toff[E_] = t;
  }
}

__global__ void route_scatter(const int* __restrict__ idx, const float* __restrict__ tkw,
                              int* __restrict__ cur, int* __restrict__ tok,
                              float* __restrict__ wsl) {
  int p = blockIdx.x * 256 + threadIdx.x;
  if (p < NSLOT) {
    int e = idx[p];
    int pos = atomicAdd(&cur[e], 1);
    tok[pos] = p >> 1;
    wsl[pos] = tkw[p];
  }
}

// ---------------------------------------------------------------------------
// wt[e][f][h] = (bf16) w[e][h][f]
__global__ void transpose_cast(const float* __restrict__ w1, const float* __restrict__ w2,
                               __hip_bfloat16* __restrict__ wt1, __hip_bfloat16* __restrict__ wt2) {
  __shared__ float t[32][33];
  const int z = blockIdx.z;
  const float* W = (z < E_ ? w1 : w2) + ((size_t)(z & 7) << 20);
  __hip_bfloat16* WT = (z < E_ ? wt1 : wt2) + ((size_t)(z & 7) << 20);
  const int h0 = blockIdx.y * 32, f0 = blockIdx.x * 32;
  const int tx = threadIdx.x, ty = threadIdx.y;  // 32 x 8
#pragma unroll
  for (int i = 0; i < 32; i += 8)
    t[ty + i][tx] = W[(size_t)(h0 + ty + i) * H_ + f0 + tx];
  __syncthreads();
#pragma unroll
  for (int i = 0; i < 32; i += 8)
    WT[(size_t)(f0 + ty + i) * H_ + h0 + tx] = __float2bfloat16(t[tx][ty + i]);
}

// ---------------------------------------------------------------------------
// Grouped GEMM, single-buffer reg-staged, raw-barrier loop:
//   { loadreg(kt+1) ; compute(kt) } -> lgkm0+bar -> dswrite(kt+1) -> lgkm0+bar
// Global loads live across barriers (counted per-reg vmcnt at ds_write).
//   EPI=0: A = gathered f32 x-rows via tok (gather FUSED); h1 = relu(AW^T+b)
//   EPI=1: A = h1 (bf16);  out[tok[p]] += wsl[p]*(AW^T+b) (f32 atomics)
#define FENCE_BAR() do {                                   \
    asm volatile("s_waitcnt lgkmcnt(0)" ::: "memory");     \
    __builtin_amdgcn_s_barrier();                          \
    __builtin_amdgcn_sched_barrier(0);                     \
  } while (0)

template <int EPI>
__launch_bounds__(256, 3)
__global__ void moe_gemm(const float* __restrict__ Xf,            // EPI=0 A source
                         const __hip_bfloat16* __restrict__ Ah,   // EPI=1 A source
                         const __hip_bfloat16* __restrict__ Wt,   // [E][H][H] (f-major)
                         const float* __restrict__ bias,          // [E][H]
                         __hip_bfloat16* __restrict__ h1out,
                         float* __restrict__ out,
                         const int* __restrict__ cnt, const int* __restrict__ offs,
                         const int* __restrict__ toff,
                         const int* __restrict__ tok, const float* __restrict__ wsl) {
  // T1: bijective XCD swizzle (NWG % 8 == 0)
  const int wgid = (blockIdx.x & 7) * (NWG / 8) + (blockIdx.x >> 3);
  const int bt = wgid >> 3;            // flat M-tile id across experts
  const int nt = wgid & 7;             // N-tile
  if (bt >= toff[E_]) return;
  int e = 0;
  while (bt >= toff[e + 1]) ++e;
  const int mt = bt - toff[e];
  const int count = cnt[e];

  const int tid = threadIdx.x;
  const int lane = tid & 63;
  const int wid = tid >> 6;
  const int wm = wid >> 1, wn = wid & 1;  // 2x2 waves -> per-wave 64x64 output
  const int l15 = lane & 15, hi = lane >> 4;

  const size_t Arow0 = (size_t)(offs[e] + mt * BM);
  const __hip_bfloat16* Bexp = Wt + ((size_t)e << 20) + (size_t)(nt * BN) * H_;

  __shared__ __hip_bfloat16 smA[BM * LDP];  // 18.4 KB
  __shared__ __hip_bfloat16 smB[BN * LDP];  // 36.9 KB total -> 4 blocks/CU by LDS

  // staging map: item i covers rows [i*32, i*32+32); thread -> row i*32+(tid>>3),
  // 16B-unit (tid&7). 8 consecutive lanes cover one contiguous row segment.
  const int srow = tid >> 3;         // 0..31
  const int sun  = (tid & 7) * 8;    // element offset within BK row

  // per-thread A row pointers (loop-invariant)
  const float*          aptrF[4];
  const __hip_bfloat16* aptrH[4];
#pragma unroll
  for (int i = 0; i < 4; ++i) {
    if constexpr (EPI == 0) {
      int p = (int)Arow0 + i * 32 + srow;
      if (p > NSLOT - 1) p = NSLOT - 1;
      aptrF[i] = Xf + (size_t)tok[p] * H_ + sun;     // garbage rows masked at epilogue
    } else {
      aptrH[i] = Ah + (Arow0 + i * 32 + srow) * H_ + sun;
    }
  }
  const __hip_bfloat16* bptr = Bexp + (size_t)srow * H_ + sun;

  // single staging register set (static indexing, rule 20)
  f32x4    fa[4][2];   // EPI=0 A staging (f32)
  short8_t ra[4];      // EPI=1 A staging (bf16)
  short8_t rb[4];

  auto loadreg = [&](int kt) {
#pragma unroll
    for (int i = 0; i < 4; ++i) {
      if constexpr (EPI == 0) {
        const f32x4* ap = (const f32x4*)(aptrF[i] + kt * BK);
        fa[i][0] = ap[0];
        fa[i][1] = ap[1];
      } else {
        ra[i] = *(const short8_t*)(aptrH[i] + kt * BK);
      }
      rb[i] = *(const short8_t*)(bptr + (size_t)(i * 32) * H_ + kt * BK);
    }
  };
  auto dswrite = [&]() {
#pragma unroll
    for (int i = 0; i < 4; ++i) {
      short8_t av;
      if constexpr (EPI == 0) {
        union { __hip_bfloat16 h[8]; short8_t v; } cv;
#pragma unroll
        for (int j = 0; j < 4; ++j) {
          cv.h[j]     = __float2bfloat16(fa[i][0][j]);
          cv.h[4 + j] = __float2bfloat16(fa[i][1][j]);
        }
        av = cv.v;
      } else {
        av = ra[i];
      }
      *(short8_t*)&smA[(i * 32 + srow) * LDP + sun] = av;   // waits vm per-reg (counted)
      *(short8_t*)&smB[(i * 32 + srow) * LDP + sun] = rb[i];
    }
  };

  f32x4 acc[4][4];
#pragma unroll
  for (int mi = 0; mi < 4; ++mi)
#pragma unroll
    for (int ni = 0; ni < 4; ++ni) acc[mi][ni] = f32x4{0.f, 0.f, 0.f, 0.f};

  auto compute = [&]() {
#pragma unroll
    for (int ks = 0; ks < 2; ++ks) {
      short8_t a[4], b[4];
#pragma unroll
      for (int mi = 0; mi < 4; ++mi)
        a[mi] = *(const short8_t*)&smA[(wm * 64 + mi * 16 + l15) * LDP + (ks * 4 + hi) * 8];
#pragma unroll
      for (int ni = 0; ni < 4; ++ni)
        b[ni] = *(const short8_t*)&smB[(wn * 64 + ni * 16 + l15) * LDP + (ks * 4 + hi) * 8];
#pragma unroll
      for (int mi = 0; mi < 4; ++mi)
#pragma unroll
        for (int ni = 0; ni < 4; ++ni)
          acc[mi][ni] = __builtin_amdgcn_mfma_f32_16x16x32_bf16(a[mi], b[ni], acc[mi][ni], 0, 0, 0);
    }
  };

  const int KT = H_ / BK;  // 16

  // prologue: tile 0 into LDS, full fence once
  loadreg(0);
  dswrite();
  FENCE_BAR();

  for (int kt = 0; kt < KT; ++kt) {
    if (kt + 1 < KT) loadreg(kt + 1);  // issue first; in flight through compute+barrier
    compute();                          // ds_reads + MFMA on tile kt
    if (kt + 1 < KT) {
      FENCE_BAR();                      // all waves done READING tile kt (lgkm only!)
      dswrite();                        // tile kt+1 (counted vmcnt waits per-reg)
      FENCE_BAR();                      // writes visible to all waves
    }
  }

  const int colb = nt * BN + wn * 64;
  if constexpr (EPI == 0) {
#pragma unroll
    for (int ni = 0; ni < 4; ++ni) {
      const int col = colb + ni * 16 + l15;
      const float bv = bias[e * H_ + col];
#pragma unroll
      for (int mi = 0; mi < 4; ++mi)
#pragma unroll
        for (int r = 0; r < 4; ++r) {
          const int lr = wm * 64 + mi * 16 + hi * 4 + r;
          if (mt * BM + lr < count) {
            float v = acc[mi][ni][r] + bv;
            h1out[(Arow0 + lr) * H_ + col] = __float2bfloat16(fmaxf(v, 0.f));
          }
        }
    }
  } else {
#pragma unroll
    for (int mi = 0; mi < 4; ++mi)
#pragma unroll
      for (int r = 0; r < 4; ++r) {
        const int lr = wm * 64 + mi * 16 + hi * 4 + r;
        if (mt * BM + lr < count) {
          const int p = (int)Arow0 + lr;
          const int t = tok[p];
          const float w = wsl[p];
#pragma unroll
          for (int ni = 0; ni < 4; ++ni) {
            const int col = colb + ni * 16 + l15;
            float v = (acc[mi][ni][r] + bias[e * H_ + col]) * w;
            atomicAdd(out + (size_t)t * H_ + col, v);
          }
        }
      }
  }
}

// ---------------------------------------------------------------------------
extern "C" void kernel_launch(void* const* d_in, const int* in_sizes, int n_in,
                              void* d_out, int out_size, void* d_ws, size_t ws_size,
                              hipStream_t stream) {
  const float* x   = (const float*)d_in[0];
  const int*   idx = (const int*)d_in[1];
  const float* tkw = (const float*)d_in[2];
  const float* w1  = (const float*)d_in[3];
  const float* b1  = (const float*)d_in[4];
  const float* w2  = (const float*)d_in[5];
  const float* b2  = (const float*)d_in[6];
  float* out = (float*)d_out;

  uint8_t* ws = (uint8_t*)d_ws;
  int*   cnt  = (int*)(ws + CNT_OFF);
  int*   cur  = (int*)(ws + CUR_OFF);
  int*   offs = (int*)(ws + OFFS_OFF);
  int*   toff = (int*)(ws + TOFF_OFF);
  int*   tok  = (int*)(ws + TOK_OFF);
  float* wsl  = (float*)(ws + WSL_OFF);
  __hip_bfloat16* h1  = (__hip_bfloat16*)(ws + H1_OFF);
  __hip_bfloat16* w1t = (__hip_bfloat16*)(ws + W1T_OFF);
  __hip_bfloat16* w2t = (__hip_bfloat16*)(ws + W2T_OFF);

  hipMemsetAsync(ws, 0, 1024, stream);
  hipMemsetAsync(d_out, 0, (size_t)out_size * sizeof(float), stream);

  transpose_cast<<<dim3(H_ / 32, H_ / 32, 2 * E_), dim3(32, 8), 0, stream>>>(w1, w2, w1t, w2t);

  route_count<<<NSLOT / 256, 256, 0, stream>>>(idx, cnt);
  route_scan<<<1, 64, 0, stream>>>(cnt, offs, cur, toff);
  route_scatter<<<NSLOT / 256, 256, 0, stream>>>(idx, tkw, cur, tok, wsl);

  moe_gemm<0><<<NWG, 256, 0, stream>>>(x, nullptr, w1t, b1, h1, nullptr,
                                       cnt, offs, toff, tok, wsl);
  moe_gemm<1><<<NWG, 256, 0, stream>>>(nullptr, h1, w2t, b2, nullptr, out,
                                       cnt, offs, toff, tok, wsl);
}

// Round 13
// 302.380 us; speedup vs baseline: 1.5894x; 1.0971x over previous
//
#include <hip/hip_runtime.h>
#include <hip/hip_bf16.h>
#include <stdint.h>

// Problem constants (B=4, S=2048, H=1024, E=8, K=2)
#define E_    8
#define H_    1024
#define NTOK  8192           // B*S
#define KSEL  2
#define NSLOT (NTOK * KSEL)  // 16384

typedef __attribute__((ext_vector_type(8))) short   short8_t;  // 8 bf16 in 4 VGPRs
typedef __attribute__((ext_vector_type(4))) float   f32x4;

// GEMM tiling: 128x128, BK=64, 4 waves. Reg-staged (global->VGPR->ds_write),
// PADDED LDS (stride 72 -> conflict-free b128 r/w), single buffer, raw
// barriers (lgkmcnt-only): global loads for kt+1 stay in flight across the
// barrier (per-reg counted vmcnt at ds_write = T4 mechanism). Best measured
// structure for this shape (R9/R12: 102-107us; m102 curve context: N=K=1024
// regime caps the m97-class structure well below its N=4096 figures).
#define BM 128
#define BN 128
#define BK 64
#define LDP 72               // padded row stride (elems)
#define MAXMT 136
#define NT    (H_ / BN)      // 8 N-tiles
#define NWG   (MAXMT * NT)   // 1088, divisible by 8 (bijective XCD swizzle)

// ---- workspace layout (bytes) ----
#define CNT_OFF   0
#define CUR_OFF   64
#define OFFS_OFF  128
#define TOFF_OFF  256
#define TOK_OFF   1024                     // NSLOT ints
#define WSL_OFF   (TOK_OFF + NSLOT * 4)    // NSLOT floats
#define AG_OFF    (1 << 18)
#define H1_OFF    (AG_OFF + (NSLOT + 256) * H_ * 2)
#define W1T_OFF   (H1_OFF + (NSLOT + 256) * H_ * 2)
#define W2T_OFF   (W1T_OFF + E_ * H_ * H_ * 2)

// ---------------------------------------------------------------------------
__global__ void route_count(const int* __restrict__ idx, int* __restrict__ cnt) {
  int p = blockIdx.x * 256 + threadIdx.x;
  if (p < NSLOT) atomicAdd(&cnt[idx[p]], 1);
}

__global__ void route_scan(const int* __restrict__ cnt, int* __restrict__ offs,
                           int* __restrict__ cur, int* __restrict__ toff) {
  if (threadIdx.x == 0) {
    int s = 0, t = 0;
    for (int e = 0; e < E_; ++e) {
      offs[e] = s; cur[e] = s; toff[e] = t;
      s += cnt[e];
      t += (cnt[e] + BM - 1) / BM;
    }
    offs[E_] = s; toff[E_] = t;
  }
}

__global__ void route_scatter(const int* __restrict__ idx, const float* __restrict__ tkw,
                              int* __restrict__ cur, int* __restrict__ tok,
                              float* __restrict__ wsl) {
  int p = blockIdx.x * 256 + threadIdx.x;
  if (p < NSLOT) {
    int e = idx[p];
    int pos = atomicAdd(&cur[e], 1);
    tok[pos] = p >> 1;
    wsl[pos] = tkw[p];
  }
}

// ---------------------------------------------------------------------------
// wt[e][f][h] = (bf16) w[e][h][f].  64x64 tiles, 256 threads.
// Loads: coalesced scalar f32 (256B/wave-instr); stores: uint2 (8B/lane,
// 128B/16-lane run). LDS staged as bf16 [64][65] (pad breaks bank stride).
__global__ void transpose_cast(const float* __restrict__ w1, const float* __restrict__ w2,
                               __hip_bfloat16* __restrict__ wt1, __hip_bfloat16* __restrict__ wt2) {
  __shared__ __hip_bfloat16 t[64][65];
  const int z = blockIdx.z;                       // 0..15: e + (w1|w2)
  const float* W = (z < E_ ? w1 : w2) + ((size_t)(z & 7) << 20);
  __hip_bfloat16* WT = (z < E_ ? wt1 : wt2) + ((size_t)(z & 7) << 20);
  const int h0 = blockIdx.y * 64, f0 = blockIdx.x * 64;
  const int tid = threadIdx.x;                    // 256
  const int tx = tid & 63, ty = tid >> 6;         // 64 x 4
#pragma unroll
  for (int i = 0; i < 16; ++i) {
    const int hl = i * 4 + ty;
    t[hl][tx] = __float2bfloat16(W[(size_t)(h0 + hl) * H_ + f0 + tx]);
  }
  __syncthreads();
  const int htx = tid & 15;                       // h quad: h = htx*4
  const int fy  = tid >> 4;                       // 0..15
#pragma unroll
  for (int j = 0; j < 4; ++j) {
    const int f = j * 16 + fy;
    union { __hip_bfloat16 h[4]; uint2 u; } v;
#pragma unroll
    for (int k = 0; k < 4; ++k) v.h[k] = t[htx * 4 + k][f];
    *reinterpret_cast<uint2*>(&WT[(size_t)(f0 + f) * H_ + h0 + htx * 4]) = v.u;
  }
}

// ---------------------------------------------------------------------------
// Grouped GEMM, single-buffer reg-staged, raw-barrier loop (R12-verified):
//   { loadreg(kt+1) ; compute(kt) } -> lgkm0+bar -> dswrite(kt+1) -> lgkm0+bar
//   EPI=0: A = gathered f32 x-rows via tok (fused); h1 = relu(AW^T+b)
//   EPI=1: A = h1 (bf16);  out[tok[p]] += wsl[p]*(AW^T+b) (f32 atomics)
#define FENCE_BAR() do {                                   \
    asm volatile("s_waitcnt lgkmcnt(0)" ::: "memory");     \
    __builtin_amdgcn_s_barrier();                          \
    __builtin_amdgcn_sched_barrier(0);                     \
  } while (0)

template <int EPI>
__launch_bounds__(256, 3)
__global__ void moe_gemm(const float* __restrict__ Xf,
                         const __hip_bfloat16* __restrict__ Ah,
                         const __hip_bfloat16* __restrict__ Wt,   // [E][H][H] (f-major)
                         const float* __restrict__ bias,          // [E][H]
                         __hip_bfloat16* __restrict__ h1out,
                         float* __restrict__ out,
                         const int* __restrict__ cnt, const int* __restrict__ offs,
                         const int* __restrict__ toff,
                         const int* __restrict__ tok, const float* __restrict__ wsl) {
  // T1: bijective XCD swizzle (NWG % 8 == 0)
  const int wgid = (blockIdx.x & 7) * (NWG / 8) + (blockIdx.x >> 3);
  const int bt = wgid >> 3;
  const int nt = wgid & 7;
  if (bt >= toff[E_]) return;
  int e = 0;
  while (bt >= toff[e + 1]) ++e;
  const int mt = bt - toff[e];
  const int count = cnt[e];

  const int tid = threadIdx.x;
  const int lane = tid & 63;
  const int wid = tid >> 6;
  const int wm = wid >> 1, wn = wid & 1;
  const int l15 = lane & 15, hi = lane >> 4;

  const size_t Arow0 = (size_t)(offs[e] + mt * BM);
  const __hip_bfloat16* Bexp = Wt + ((size_t)e << 20) + (size_t)(nt * BN) * H_;

  __shared__ __hip_bfloat16 smA[BM * LDP];  // 18.4 KB
  __shared__ __hip_bfloat16 smB[BN * LDP];  // 36.9 KB total

  const int srow = tid >> 3;         // 0..31
  const int sun  = (tid & 7) * 8;

  const float*          aptrF[4];
  const __hip_bfloat16* aptrH[4];
#pragma unroll
  for (int i = 0; i < 4; ++i) {
    if constexpr (EPI == 0) {
      int p = (int)Arow0 + i * 32 + srow;
      if (p > NSLOT - 1) p = NSLOT - 1;
      aptrF[i] = Xf + (size_t)tok[p] * H_ + sun;
    } else {
      aptrH[i] = Ah + (Arow0 + i * 32 + srow) * H_ + sun;
    }
  }
  const __hip_bfloat16* bptr = Bexp + (size_t)srow * H_ + sun;

  f32x4    fa[4][2];
  short8_t ra[4];
  short8_t rb[4];

  auto loadreg = [&](int kt) {
#pragma unroll
    for (int i = 0; i < 4; ++i) {
      if constexpr (EPI == 0) {
        const f32x4* ap = (const f32x4*)(aptrF[i] + kt * BK);
        fa[i][0] = ap[0];
        fa[i][1] = ap[1];
      } else {
        ra[i] = *(const short8_t*)(aptrH[i] + kt * BK);
      }
      rb[i] = *(const short8_t*)(bptr + (size_t)(i * 32) * H_ + kt * BK);
    }
  };
  auto dswrite = [&]() {
#pragma unroll
    for (int i = 0; i < 4; ++i) {
      short8_t av;
      if constexpr (EPI == 0) {
        union { __hip_bfloat16 h[8]; short8_t v; } cv;
#pragma unroll
        for (int j = 0; j < 4; ++j) {
          cv.h[j]     = __float2bfloat16(fa[i][0][j]);
          cv.h[4 + j] = __float2bfloat16(fa[i][1][j]);
        }
        av = cv.v;
      } else {
        av = ra[i];
      }
      *(short8_t*)&smA[(i * 32 + srow) * LDP + sun] = av;
      *(short8_t*)&smB[(i * 32 + srow) * LDP + sun] = rb[i];
    }
  };

  f32x4 acc[4][4];
#pragma unroll
  for (int mi = 0; mi < 4; ++mi)
#pragma unroll
    for (int ni = 0; ni < 4; ++ni) acc[mi][ni] = f32x4{0.f, 0.f, 0.f, 0.f};

  auto compute = [&]() {
#pragma unroll
    for (int ks = 0; ks < 2; ++ks) {
      short8_t a[4], b[4];
#pragma unroll
      for (int mi = 0; mi < 4; ++mi)
        a[mi] = *(const short8_t*)&smA[(wm * 64 + mi * 16 + l15) * LDP + (ks * 4 + hi) * 8];
#pragma unroll
      for (int ni = 0; ni < 4; ++ni)
        b[ni] = *(const short8_t*)&smB[(wn * 64 + ni * 16 + l15) * LDP + (ks * 4 + hi) * 8];
#pragma unroll
      for (int mi = 0; mi < 4; ++mi)
#pragma unroll
        for (int ni = 0; ni < 4; ++ni)
          acc[mi][ni] = __builtin_amdgcn_mfma_f32_16x16x32_bf16(a[mi], b[ni], acc[mi][ni], 0, 0, 0);
    }
  };

  const int KT = H_ / BK;  // 16

  loadreg(0);
  dswrite();
  FENCE_BAR();

  for (int kt = 0; kt < KT; ++kt) {
    if (kt + 1 < KT) loadreg(kt + 1);  // in flight through compute + barrier
    compute();
    if (kt + 1 < KT) {
      FENCE_BAR();                      // all waves done reading tile kt
      dswrite();                        // counted per-reg vmcnt waits only
      FENCE_BAR();                      // writes visible
    }
  }

  // ---- epilogue: per-(mi,r) hoisted bound check (16 checks, not 64) ----
  const int colb = nt * BN + wn * 64;
  float bv[4];
#pragma unroll
  for (int ni = 0; ni < 4; ++ni) bv[ni] = bias[e * H_ + colb + ni * 16 + l15];

  if constexpr (EPI == 0) {
#pragma unroll
    for (int mi = 0; mi < 4; ++mi)
#pragma unroll
      for (int r = 0; r < 4; ++r) {
        const int lr = wm * 64 + mi * 16 + hi * 4 + r;
        if (mt * BM + lr < count) {
          __hip_bfloat16* rp = h1out + (Arow0 + lr) * H_ + colb;
#pragma unroll
          for (int ni = 0; ni < 4; ++ni) {
            float v = acc[mi][ni][r] + bv[ni];
            rp[ni * 16 + l15] = __float2bfloat16(fmaxf(v, 0.f));
          }
        }
      }
  } else {
#pragma unroll
    for (int mi = 0; mi < 4; ++mi)
#pragma unroll
      for (int r = 0; r < 4; ++r) {
        const int lr = wm * 64 + mi * 16 + hi * 4 + r;
        if (mt * BM + lr < count) {
          const int p = (int)Arow0 + lr;
          float* rp = out + (size_t)tok[p] * H_ + colb;
          const float w = wsl[p];
#pragma unroll
          for (int ni = 0; ni < 4; ++ni)
            atomicAdd(rp + ni * 16 + l15, (acc[mi][ni][r] + bv[ni]) * w);
        }
      }
  }
}

// ---------------------------------------------------------------------------
extern "C" void kernel_launch(void* const* d_in, const int* in_sizes, int n_in,
                              void* d_out, int out_size, void* d_ws, size_t ws_size,
                              hipStream_t stream) {
  const float* x   = (const float*)d_in[0];
  const int*   idx = (const int*)d_in[1];
  const float* tkw = (const float*)d_in[2];
  const float* w1  = (const float*)d_in[3];
  const float* b1  = (const float*)d_in[4];
  const float* w2  = (const float*)d_in[5];
  const float* b2  = (const float*)d_in[6];
  float* out = (float*)d_out;

  uint8_t* ws = (uint8_t*)d_ws;
  int*   cnt  = (int*)(ws + CNT_OFF);
  int*   cur  = (int*)(ws + CUR_OFF);
  int*   offs = (int*)(ws + OFFS_OFF);
  int*   toff = (int*)(ws + TOFF_OFF);
  int*   tok  = (int*)(ws + TOK_OFF);
  float* wsl  = (float*)(ws + WSL_OFF);
  __hip_bfloat16* h1  = (__hip_bfloat16*)(ws + H1_OFF);
  __hip_bfloat16* w1t = (__hip_bfloat16*)(ws + W1T_OFF);
  __hip_bfloat16* w2t = (__hip_bfloat16*)(ws + W2T_OFF);

  hipMemsetAsync(ws, 0, 1024, stream);
  hipMemsetAsync(d_out, 0, (size_t)out_size * sizeof(float), stream);

  transpose_cast<<<dim3(H_ / 64, H_ / 64, 2 * E_), 256, 0, stream>>>(w1, w2, w1t, w2t);

  route_count<<<NSLOT / 256, 256, 0, stream>>>(idx, cnt);
  route_scan<<<1, 64, 0, stream>>>(cnt, offs, cur, toff);
  route_scatter<<<NSLOT / 256, 256, 0, stream>>>(idx, tkw, cur, tok, wsl);

  moe_gemm<0><<<NWG, 256, 0, stream>>>(x, nullptr, w1t, b1, h1, nullptr,
                                       cnt, offs, toff, tok, wsl);
  moe_gemm<1><<<NWG, 256, 0, stream>>>(nullptr, h1, w2t, b2, nullptr, out,
                                       cnt, offs, toff, tok, wsl);
}

// Round 14
// 300.509 us; speedup vs baseline: 1.5993x; 1.0062x over previous
//
#include <hip/hip_runtime.h>
#include <hip/hip_bf16.h>
#include <stdint.h>

// Problem constants (B=4, S=2048, H=1024, E=8, K=2)
#define E_    8
#define H_    1024
#define NTOK  8192           // B*S
#define KSEL  2
#define NSLOT (NTOK * KSEL)  // 16384

typedef __attribute__((ext_vector_type(8))) short   short8_t;  // 8 bf16 in 4 VGPRs
typedef __attribute__((ext_vector_type(4))) float   f32x4;

// GEMM tiling: 128x128, BK=64, 4 waves. Reg-staged bf16 (global->VGPR->ds_write),
// PADDED LDS (stride 72 -> conflict-free b128 r/w), single buffer, raw barriers
// (lgkmcnt-only): loads for kt+1 stay in flight across the barrier (per-reg
// counted vmcnt at ds_write = T4 mechanism). lb(256,4): LDS 36.9KB -> 4 blk/CU.
#define BM 128
#define BN 128
#define BK 64
#define LDP 72               // padded row stride (elems); 144B, 16B-aligned
#define MAXMT 136
#define NT    (H_ / BN)      // 8 N-tiles
#define NWG   (MAXMT * NT)   // 1088, divisible by 8 (bijective XCD swizzle)

// ---- workspace layout (bytes) ----
#define CNT_OFF   0
#define CUR_OFF   64
#define TOK_OFF   1024                     // NSLOT ints
#define WSL_OFF   (TOK_OFF + NSLOT * 4)    // NSLOT floats
#define XB_OFF    (1 << 18)                              // bf16 x (16.7 MB)
#define H1_OFF    (XB_OFF + (NSLOT + 256) * H_ * 2)      // keeps prior extent
#define W1T_OFF   (H1_OFF + (NSLOT + 256) * H_ * 2)
#define W2T_OFF   (W1T_OFF + E_ * H_ * H_ * 2)

// ---------------------------------------------------------------------------
__global__ void route_count(const int* __restrict__ idx, int* __restrict__ cnt) {
  int p = blockIdx.x * 256 + threadIdx.x;
  if (p < NSLOT) atomicAdd(&cnt[idx[p]], 1);
}

// scatter with INLINE prefix (route_scan folded in; cnt is final counts here)
__global__ void route_scatter(const int* __restrict__ idx, const float* __restrict__ tkw,
                              const int* __restrict__ cnt, int* __restrict__ cur,
                              int* __restrict__ tok, float* __restrict__ wsl) {
  int p = blockIdx.x * 256 + threadIdx.x;
  if (p < NSLOT) {
    const int e = idx[p];
    int off = 0;
#pragma unroll
    for (int i = 0; i < E_; ++i) off += (i < e) ? cnt[i] : 0;
    const int pos = off + atomicAdd(&cur[e], 1);
    tok[pos] = p >> 1;
    wsl[pos] = tkw[p];
  }
}

// ---------------------------------------------------------------------------
// xb = (bf16) x   — 16 elems/thread, 2048 blocks
__global__ void xcast(const float* __restrict__ x, __hip_bfloat16* __restrict__ xb) {
  const size_t base = ((size_t)blockIdx.x * 256 + threadIdx.x) * 16;
#pragma unroll
  for (int h = 0; h < 2; ++h) {
    f32x4 v0 = *(const f32x4*)(x + base + h * 8);
    f32x4 v1 = *(const f32x4*)(x + base + h * 8 + 4);
    union { __hip_bfloat16 b[8]; uint2 u[2]; } cv;
#pragma unroll
    for (int j = 0; j < 4; ++j) {
      cv.b[j]     = __float2bfloat16(v0[j]);
      cv.b[4 + j] = __float2bfloat16(v1[j]);
    }
    *(uint2*)(xb + base + h * 8)     = cv.u[0];
    *(uint2*)(xb + base + h * 8 + 4) = cv.u[1];
  }
}

// ---------------------------------------------------------------------------
// wt[e][f][h] = (bf16) w[e][h][f].  64x64 tiles, 256 threads (R13-verified).
__global__ void transpose_cast(const float* __restrict__ w1, const float* __restrict__ w2,
                               __hip_bfloat16* __restrict__ wt1, __hip_bfloat16* __restrict__ wt2) {
  __shared__ __hip_bfloat16 t[64][65];
  const int z = blockIdx.z;                       // 0..15: e + (w1|w2)
  const float* W = (z < E_ ? w1 : w2) + ((size_t)(z & 7) << 20);
  __hip_bfloat16* WT = (z < E_ ? wt1 : wt2) + ((size_t)(z & 7) << 20);
  const int h0 = blockIdx.y * 64, f0 = blockIdx.x * 64;
  const int tid = threadIdx.x;
  const int tx = tid & 63, ty = tid >> 6;         // 64 x 4
#pragma unroll
  for (int i = 0; i < 16; ++i) {
    const int hl = i * 4 + ty;
    t[hl][tx] = __float2bfloat16(W[(size_t)(h0 + hl) * H_ + f0 + tx]);
  }
  __syncthreads();
  const int htx = tid & 15;
  const int fy  = tid >> 4;
#pragma unroll
  for (int j = 0; j < 4; ++j) {
    const int f = j * 16 + fy;
    union { __hip_bfloat16 h[4]; uint2 u; } v;
#pragma unroll
    for (int k = 0; k < 4; ++k) v.h[k] = t[htx * 4 + k][f];
    *reinterpret_cast<uint2*>(&WT[(size_t)(f0 + f) * H_ + h0 + htx * 4]) = v.u;
  }
}

// ---------------------------------------------------------------------------
// Grouped GEMM, single-buffer reg-staged, raw-barrier loop (R12/R13-verified):
//   { loadreg(kt+1) ; compute(kt) } -> lgkm0+bar -> dswrite(kt+1) -> lgkm0+bar
//   EPI=0: A = xb rows gathered via tok;  h1 = relu(AW^T+b)
//   EPI=1: A = h1 rows (linear);          out[tok[p]] += wsl[p]*(AW^T+b)
#define FENCE_BAR() do {                                   \
    asm volatile("s_waitcnt lgkmcnt(0)" ::: "memory");     \
    __builtin_amdgcn_s_barrier();                          \
    __builtin_amdgcn_sched_barrier(0);                     \
  } while (0)

template <int EPI>
__launch_bounds__(256, 4)
__global__ void moe_gemm(const __hip_bfloat16* __restrict__ Asrc,  // xb (EPI=0) / h1 (EPI=1)
                         const __hip_bfloat16* __restrict__ Wt,    // [E][H][H] (f-major)
                         const float* __restrict__ bias,           // [E][H]
                         __hip_bfloat16* __restrict__ h1out,
                         float* __restrict__ out,
                         const int* __restrict__ cnt,
                         const int* __restrict__ tok, const float* __restrict__ wsl) {
  // T1: bijective XCD swizzle (NWG % 8 == 0)
  const int wgid = (blockIdx.x & 7) * (NWG / 8) + (blockIdx.x >> 3);
  const int bt = wgid >> 3;
  const int nt = wgid & 7;

  // inline offs/toff prefix from cnt[8] (route_scan folded in)
  int cn[E_];
#pragma unroll
  for (int i = 0; i < E_; ++i) cn[i] = cnt[i];
  int e = -1, mt = 0, count = 0, arow0 = 0;
  {
    int tacc = 0, sacc = 0;
#pragma unroll
    for (int i = 0; i < E_; ++i) {
      const int nti = (cn[i] + BM - 1) / BM;
      if (e < 0 && bt < tacc + nti) { e = i; mt = bt - tacc; count = cn[i]; arow0 = sacc + mt * BM; }
      tacc += nti; sacc += cn[i];
    }
  }
  if (e < 0) return;
  const size_t Arow0 = (size_t)arow0;

  const int tid = threadIdx.x;
  const int lane = tid & 63;
  const int wid = tid >> 6;
  const int wm = wid >> 1, wn = wid & 1;
  const int l15 = lane & 15, hi = lane >> 4;

  const __hip_bfloat16* Bexp = Wt + ((size_t)e << 20) + (size_t)(nt * BN) * H_;

  __shared__ __hip_bfloat16 smA[BM * LDP];  // 18.4 KB
  __shared__ __hip_bfloat16 smB[BN * LDP];  // 36.9 KB total -> 4 blocks/CU

  const int srow = tid >> 3;         // 0..31
  const int sun  = (tid & 7) * 8;

  const __hip_bfloat16* aptr[4];
#pragma unroll
  for (int i = 0; i < 4; ++i) {
    if constexpr (EPI == 0) {
      int p = arow0 + i * 32 + srow;
      if (p > NSLOT - 1) p = NSLOT - 1;
      aptr[i] = Asrc + (size_t)tok[p] * H_ + sun;     // gathered bf16 x rows
    } else {
      aptr[i] = Asrc + (Arow0 + i * 32 + srow) * H_ + sun;  // linear h1 rows
    }
  }
  const __hip_bfloat16* bptr = Bexp + (size_t)srow * H_ + sun;

  short8_t ra[4], rb[4];

  auto loadreg = [&](int kt) {
#pragma unroll
    for (int i = 0; i < 4; ++i) {
      ra[i] = *(const short8_t*)(aptr[i] + kt * BK);
      rb[i] = *(const short8_t*)(bptr + (size_t)(i * 32) * H_ + kt * BK);
    }
  };
  auto dswrite = [&]() {
#pragma unroll
    for (int i = 0; i < 4; ++i) {
      *(short8_t*)&smA[(i * 32 + srow) * LDP + sun] = ra[i];
      *(short8_t*)&smB[(i * 32 + srow) * LDP + sun] = rb[i];
    }
  };

  f32x4 acc[4][4];
#pragma unroll
  for (int mi = 0; mi < 4; ++mi)
#pragma unroll
    for (int ni = 0; ni < 4; ++ni) acc[mi][ni] = f32x4{0.f, 0.f, 0.f, 0.f};

  auto compute = [&]() {
#pragma unroll
    for (int ks = 0; ks < 2; ++ks) {
      short8_t a[4], b[4];
#pragma unroll
      for (int mi = 0; mi < 4; ++mi)
        a[mi] = *(const short8_t*)&smA[(wm * 64 + mi * 16 + l15) * LDP + (ks * 4 + hi) * 8];
#pragma unroll
      for (int ni = 0; ni < 4; ++ni)
        b[ni] = *(const short8_t*)&smB[(wn * 64 + ni * 16 + l15) * LDP + (ks * 4 + hi) * 8];
#pragma unroll
      for (int mi = 0; mi < 4; ++mi)
#pragma unroll
        for (int ni = 0; ni < 4; ++ni)
          acc[mi][ni] = __builtin_amdgcn_mfma_f32_16x16x32_bf16(a[mi], b[ni], acc[mi][ni], 0, 0, 0);
    }
  };

  const int KT = H_ / BK;  // 16

  loadreg(0);
  dswrite();
  FENCE_BAR();

  for (int kt = 0; kt < KT; ++kt) {
    if (kt + 1 < KT) loadreg(kt + 1);  // in flight through compute + barrier
    compute();
    if (kt + 1 < KT) {
      FENCE_BAR();                      // all waves done reading tile kt
      dswrite();                        // counted per-reg vmcnt waits only
      FENCE_BAR();                      // writes visible
    }
  }

  // ---- epilogue: per-(mi,r) hoisted bound check (R13-verified) ----
  const int colb = nt * BN + wn * 64;
  float bv[4];
#pragma unroll
  for (int ni = 0; ni < 4; ++ni) bv[ni] = bias[e * H_ + colb + ni * 16 + l15];

  if constexpr (EPI == 0) {
#pragma unroll
    for (int mi = 0; mi < 4; ++mi)
#pragma unroll
      for (int r = 0; r < 4; ++r) {
        const int lr = wm * 64 + mi * 16 + hi * 4 + r;
        if (mt * BM + lr < count) {
          __hip_bfloat16* rp = h1out + (Arow0 + lr) * H_ + colb;
#pragma unroll
          for (int ni = 0; ni < 4; ++ni) {
            float v = acc[mi][ni][r] + bv[ni];
            rp[ni * 16 + l15] = __float2bfloat16(fmaxf(v, 0.f));
          }
        }
      }
  } else {
#pragma unroll
    for (int mi = 0; mi < 4; ++mi)
#pragma unroll
      for (int r = 0; r < 4; ++r) {
        const int lr = wm * 64 + mi * 16 + hi * 4 + r;
        if (mt * BM + lr < count) {
          const int p = arow0 + lr;
          float* rp = out + (size_t)tok[p] * H_ + colb;
          const float w = wsl[p];
#pragma unroll
          for (int ni = 0; ni < 4; ++ni)
            atomicAdd(rp + ni * 16 + l15, (acc[mi][ni][r] + bv[ni]) * w);
        }
      }
  }
}

// ---------------------------------------------------------------------------
extern "C" void kernel_launch(void* const* d_in, const int* in_sizes, int n_in,
                              void* d_out, int out_size, void* d_ws, size_t ws_size,
                              hipStream_t stream) {
  const float* x   = (const float*)d_in[0];
  const int*   idx = (const int*)d_in[1];
  const float* tkw = (const float*)d_in[2];
  const float* w1  = (const float*)d_in[3];
  const float* b1  = (const float*)d_in[4];
  const float* w2  = (const float*)d_in[5];
  const float* b2  = (const float*)d_in[6];
  float* out = (float*)d_out;

  uint8_t* ws = (uint8_t*)d_ws;
  int*   cnt  = (int*)(ws + CNT_OFF);
  int*   cur  = (int*)(ws + CUR_OFF);
  int*   tok  = (int*)(ws + TOK_OFF);
  float* wsl  = (float*)(ws + WSL_OFF);
  __hip_bfloat16* xb  = (__hip_bfloat16*)(ws + XB_OFF);
  __hip_bfloat16* h1  = (__hip_bfloat16*)(ws + H1_OFF);
  __hip_bfloat16* w1t = (__hip_bfloat16*)(ws + W1T_OFF);
  __hip_bfloat16* w2t = (__hip_bfloat16*)(ws + W2T_OFF);

  hipMemsetAsync(ws, 0, 1024, stream);                                // cnt + cur
  hipMemsetAsync(d_out, 0, (size_t)out_size * sizeof(float), stream);

  xcast<<<NTOK * H_ / (256 * 16), 256, 0, stream>>>(x, xb);
  transpose_cast<<<dim3(H_ / 64, H_ / 64, 2 * E_), 256, 0, stream>>>(w1, w2, w1t, w2t);

  route_count<<<NSLOT / 256, 256, 0, stream>>>(idx, cnt);
  route_scatter<<<NSLOT / 256, 256, 0, stream>>>(idx, tkw, cnt, cur, tok, wsl);

  moe_gemm<0><<<NWG, 256, 0, stream>>>(xb, w1t, b1, h1, nullptr, cnt, tok, wsl);
  moe_gemm<1><<<NWG, 256, 0, stream>>>(h1, w2t, b2, nullptr, out, cnt, tok, wsl);
}